// Round 1
// baseline (74.016 us; speedup 1.0000x reference)
//
#include <hip/hip_runtime.h>

#define BM 64
#define BN 64
#define BK 32
#define VIG 0.75f

// Kernel 1: split-K fuzzy-AND accumulation (min-plus GEMM).
// Grid: (N/BM, C/BN, ksplit). Block: 256 threads, each computes a 4x4 output tile.
// LDS tiles stored [K][M] with XOR swizzle on the 4-float granule index:
//   element (k, m) lives at k*64 + (((m>>2) ^ ((k>>2)&3))<<2 | (m&3)).
// Staging stores land <=2-way bank conflicts (free), fragment b128 reads conflict-free.
__global__ __launch_bounds__(256) void fuzzy_scores_kernel(
    const float* __restrict__ x, const float* __restrict__ w,
    float* __restrict__ out0, float* __restrict__ wsbuf,
    int N, int C, int D, int kchunk)
{
    __shared__ float sA[BK * BM];
    __shared__ float sB[BK * BN];

    const int t  = threadIdx.x;
    const int cx = t & 15;   // column group (coalesced epilogue stores)
    const int ry = t >> 4;   // row group
    const int bx = blockIdx.x, by = blockIdx.y, bz = blockIdx.z;
    const int d0 = bz * kchunk;

    float acc[4][4];
#pragma unroll
    for (int i = 0; i < 4; ++i)
#pragma unroll
        for (int j = 0; j < 4; ++j) acc[i][j] = 0.f;

    for (int kb = 0; kb < kchunk; kb += BK) {
        __syncthreads();  // protect LDS from previous iteration's readers
#pragma unroll
        for (int l = 0; l < 2; ++l) {
            const int q  = l * 256 + t;       // 0..511
            const int rr = q >> 3;            // row within tile, 0..63
            const int kq = (q & 7) << 2;      // k offset, multiple of 4
            const int c3 = q & 3;             // == (k>>2)&3 for k in [kq, kq+3]
            const int gb = ((((rr >> 2) ^ c3) << 2) | (rr & 3));

            const float4 v = *(const float4*)(x + (size_t)(bx * BM + rr) * D + d0 + kb + kq);
            sA[(kq + 0) * BM + gb] = v.x;
            sA[(kq + 1) * BM + gb] = v.y;
            sA[(kq + 2) * BM + gb] = v.z;
            sA[(kq + 3) * BM + gb] = v.w;

            const float4 u = *(const float4*)(w + (size_t)(by * BN + rr) * D + d0 + kb + kq);
            sB[(kq + 0) * BN + gb] = u.x;
            sB[(kq + 1) * BN + gb] = u.y;
            sB[(kq + 2) * BN + gb] = u.z;
            sB[(kq + 3) * BN + gb] = u.w;
        }
        __syncthreads();

#pragma unroll
        for (int k = 0; k < BK; ++k) {
            const int c3 = (k >> 2) & 3;
            const float4 a = *(const float4*)&sA[k * BM + ((ry ^ c3) << 2)];
            const float4 b = *(const float4*)&sB[k * BN + ((cx ^ c3) << 2)];
            const float av[4] = {a.x, a.y, a.z, a.w};
            const float bv[4] = {b.x, b.y, b.z, b.w};
#pragma unroll
            for (int i = 0; i < 4; ++i)
#pragma unroll
                for (int j = 0; j < 4; ++j)
                    acc[i][j] += fminf(av[i], bv[j]);
        }
    }

    float* dst = (bz == 0) ? out0 : (wsbuf + (size_t)(bz - 1) * N * C);
    const int col = by * BN + (cx << 2);
#pragma unroll
    for (int i = 0; i < 4; ++i) {
        const int row = bx * BM + (ry << 2) + i;
        *(float4*)(dst + (size_t)row * C + col) =
            make_float4(acc[i][0], acc[i][1], acc[i][2], acc[i][3]);
    }
}

// Kernel 2: per-row finish. Sums split-K partials, divides by row-sum of x,
// applies vigilance gate, writes final scores, computes argmax (first index on
// ties -> matches jnp.argmax; all-zero row -> index 0).
// Grid: N blocks of 256 threads (D == 256 assumed).
__global__ __launch_bounds__(256) void fuzzy_finish_kernel(
    const float* __restrict__ x, float* __restrict__ out,
    const float* __restrict__ wsbuf, int N, int C, int D, int ksplit)
{
    const int n = blockIdx.x;
    const int t = threadIdx.x;
    const int lane = t & 63;
    const int wid  = t >> 6;

    // row sum of x
    float v = x[(size_t)n * D + t];
#pragma unroll
    for (int s = 1; s < 64; s <<= 1) v += __shfl_xor(v, s);
    __shared__ float wsum[4];
    if (lane == 0) wsum[wid] = v;
    __syncthreads();
    const float sumx = wsum[0] + wsum[1] + wsum[2] + wsum[3];

    float best = -1.f;
    int   bidx = 0;
    for (int j = 0; j < C; j += 256) {
        const int c = j + t;
        const size_t off = (size_t)n * C + c;
        float raw = out[off];
        for (int p = 1; p < ksplit; ++p)
            raw += wsbuf[(size_t)(p - 1) * N * C + off];
        const float m = raw / sumx;
        const float s = (m >= VIG) ? m : 0.f;
        out[off] = s;
        if (s > best) { best = s; bidx = c; }  // strictly greater: first index wins ties
    }

    // wave argmax reduce (lexicographic max on (value, -index))
#pragma unroll
    for (int s2 = 1; s2 < 64; s2 <<= 1) {
        const float ov = __shfl_xor(best, s2);
        const int   oi = __shfl_xor(bidx, s2);
        if (ov > best || (ov == best && oi < bidx)) { best = ov; bidx = oi; }
    }
    __shared__ float bvs[4];
    __shared__ int   bis[4];
    if (lane == 0) { bvs[wid] = best; bis[wid] = bidx; }
    __syncthreads();
    if (t == 0) {
        for (int w2 = 1; w2 < 4; ++w2) {
            if (bvs[w2] > best || (bvs[w2] == best && bis[w2] < bidx)) {
                best = bvs[w2];
                bidx = bis[w2];
            }
        }
        out[(size_t)N * C + n] = (float)bidx;
    }
}

extern "C" void kernel_launch(void* const* d_in, const int* in_sizes, int n_in,
                              void* d_out, int out_size, void* d_ws, size_t ws_size,
                              hipStream_t stream) {
    const float* x = (const float*)d_in[0];
    const float* w = (const float*)d_in[1];
    float* out = (float*)d_out;
    float* ws  = (float*)d_ws;

    const int D = 256;
    const int N = in_sizes[0] / D;   // 1024
    const int C = in_sizes[1] / D;   // 512

    const size_t partial_bytes = (size_t)N * C * sizeof(float);  // 2 MB
    int ksplit = 1;
    if (ws_size >= 3 * partial_bytes)      ksplit = 4;
    else if (ws_size >= partial_bytes)     ksplit = 2;
    const int kchunk = D / ksplit;

    dim3 grid(N / BM, C / BN, ksplit);
    fuzzy_scores_kernel<<<grid, 256, 0, stream>>>(x, w, out, ws, N, C, D, kchunk);
    fuzzy_finish_kernel<<<N, 256, 0, stream>>>(x, out, ws, N, C, D, ksplit);
}